// Round 10
// baseline (480.279 us; speedup 1.0000x reference)
//
#include <hip/hip_runtime.h>
#include <cstdint>

// GIN model: N=100000, F=64, H=128, C=10, E=1600000.
// R10: gather2 reverted to uint2 (R8; uint4 was neutral -> L2-miss-path bound).
// MFMA kernels read A/W fragments direct from global (W is L2-resident, A coalesced)
// -> LDS 69.6->34.8 KB, 2->4 blocks/CU. chunkscan+bscan merged (last-block trick).
// 8 dispatches.

#define NN 100000
#define FF 64
#define HH 128
#define CC 10
#define EE 1600000
#define BN_EPS 1e-5f
#define MBLK 128
#define NBLK_LIN ((NN + MBLK - 1) / MBLK)  // 782
#define BSHIFT 7
#define NBUCK ((NN + 127) / 128)           // 782
#define CHUNK 16384
#define NB_CH ((EE + CHUNK - 1) / CHUNK)   // 98
#define NB_CVT 3125                        // 100000*64/8/256 exactly
#define TW (8192 + 4 * 16384 + 2048)
#define TWB ((TW + 255) / 256)
#define LDSE 3072

typedef __attribute__((ext_vector_type(8))) short bf16x8;
typedef __attribute__((ext_vector_type(4))) float f32x4;

__device__ inline unsigned short f2bf(float f) {
    unsigned int u = __float_as_uint(f);
    unsigned int r = (u + 0x7fffu + ((u >> 16) & 1u)) >> 16;
    return (unsigned short)r;
}
__device__ inline float b2f(unsigned short h) {
    return __uint_as_float(((unsigned int)h) << 16);
}
__device__ inline unsigned int pack2(float a, float b) {
    return (unsigned int)f2bf(a) | ((unsigned int)f2bf(b) << 16);
}
__device__ inline int detect_i64(const unsigned int* e) {
    return (e[1] | e[3] | e[5] | e[7]) == 0u;
}
__device__ inline int edge_dst(const void* eiv, int f, int e) {
    return f ? (int)((const long long*)eiv)[EE + e] : ((const int*)eiv)[EE + e];
}
__device__ inline int edge_src(const void* eiv, int f, int e) {
    return f ? (int)((const long long*)eiv)[e] : ((const int*)eiv)[e];
}

// ---------------- prep: x->bf16, weight transpose, zeroing, per-chunk dst hist ----------------
__global__ __launch_bounds__(256) void cvtprep_kernel(
    const float* __restrict__ x, unsigned short* __restrict__ xb,
    const float* __restrict__ w1a, const float* __restrict__ w1b,
    const float* __restrict__ w2a, const float* __restrict__ w2b,
    const float* __restrict__ mw1, const float* __restrict__ mw2,
    unsigned short* __restrict__ wt1a, unsigned short* __restrict__ wt1b,
    unsigned short* __restrict__ wt2a, unsigned short* __restrict__ wt2b,
    unsigned short* __restrict__ wtm1, unsigned short* __restrict__ wtm2,
    float* __restrict__ stats, int* __restrict__ donecnt,
    const void* __restrict__ eiv, int* __restrict__ chunkhist) {
    __shared__ int hist[NBUCK];
    const int tid = threadIdx.x;
    const int b = blockIdx.x;
    if (b == 0) {
        for (int i = tid; i < 512; i += 256) stats[i] = 0.f;
        if (tid == 0) donecnt[0] = 0;
    }
    if (b < NB_CVT) {
        int i = b * 256 + tid;
        float4 a = ((const float4*)x)[i * 2];
        float4 c = ((const float4*)x)[i * 2 + 1];
        uint4 o;
        o.x = pack2(a.x, a.y); o.y = pack2(a.z, a.w);
        o.z = pack2(c.x, c.y); o.w = pack2(c.z, c.w);
        ((uint4*)xb)[i] = o;
        return;
    }
    if (b < NB_CVT + TWB) {
        int idx = (b - NB_CVT) * 256 + tid;
        if (idx < 8192) {
            int k = idx >> 7, n = idx & 127;
            wt1a[n * 64 + k] = f2bf(w1a[idx]);
        } else if (idx < 8192 + 16384) {
            int t = idx - 8192; int k = t >> 7, n = t & 127;
            wt1b[n * 128 + k] = f2bf(w1b[t]);
        } else if (idx < 8192 + 2 * 16384) {
            int t = idx - (8192 + 16384); int k = t >> 7, n = t & 127;
            wt2a[n * 128 + k] = f2bf(w2a[t]);
        } else if (idx < 8192 + 3 * 16384) {
            int t = idx - (8192 + 2 * 16384); int k = t >> 7, n = t & 127;
            wt2b[n * 128 + k] = f2bf(w2b[t]);
        } else if (idx < 8192 + 4 * 16384) {
            int t = idx - (8192 + 3 * 16384); int k = t >> 7, n = t & 127;
            wtm1[n * 128 + k] = f2bf(mw1[t]);
        } else if (idx < TW) {
            int t = idx - (8192 + 4 * 16384); int n = t & 15, k = t >> 4;
            wtm2[n * 128 + k] = (n < CC) ? f2bf(mw2[k * CC + n]) : (unsigned short)0;
        }
        return;
    }
    const int ch = b - NB_CVT - TWB;
    const int f = detect_i64((const unsigned int*)eiv);
    for (int i = tid; i < NBUCK; i += 256) hist[i] = 0;
    __syncthreads();
    int beg = ch * CHUNK, end = min(beg + CHUNK, EE);
    for (int e = beg + tid; e < end; e += 256)
        atomicAdd(&hist[edge_dst(eiv, f, e) >> BSHIFT], 1);
    __syncthreads();
    for (int i = tid; i < NBUCK; i += 256) chunkhist[ch * NBUCK + i] = hist[i];
}

// ---------------- chunkscan (+ bucket scan in last block) ----------------
__global__ __launch_bounds__(128) void chunkscan_kernel(int* __restrict__ chunkhist,
                                                        int* __restrict__ gbcount,
                                                        int* __restrict__ gbstart,
                                                        int* __restrict__ rowstart,
                                                        int* __restrict__ donecnt) {
    __shared__ int s[128];
    __shared__ int isLast;
    const int b = blockIdx.x, tid = threadIdx.x;
    int v = (tid < NB_CH) ? chunkhist[tid * NBUCK + b] : 0;
    s[tid] = v;
    __syncthreads();
    for (int off = 1; off < 128; off <<= 1) {
        int t = (tid >= off) ? s[tid - off] : 0;
        __syncthreads();
        s[tid] += t;
        __syncthreads();
    }
    if (tid < NB_CH) chunkhist[tid * NBUCK + b] = s[tid] - v;
    if (tid == 127) gbcount[b] = s[127];
    __threadfence();
    __syncthreads();
    if (tid == 0) isLast = (atomicAdd(donecnt, 1) == NBUCK - 1) ? 1 : 0;
    __syncthreads();
    if (!isLast) return;
    __threadfence();  // acquire: other blocks' gbcount now visible
    int carry = 0;
    for (int c0 = 0; c0 < NBUCK; c0 += 128) {
        int vv = (c0 + tid < NBUCK) ? gbcount[c0 + tid] : 0;
        __syncthreads();
        s[tid] = vv;
        __syncthreads();
        for (int off = 1; off < 128; off <<= 1) {
            int t = (tid >= off) ? s[tid - off] : 0;
            __syncthreads();
            s[tid] += t;
            __syncthreads();
        }
        if (c0 + tid < NBUCK) gbstart[c0 + tid] = carry + s[tid] - vv;
        carry += s[127];
        __syncthreads();
    }
    if (tid == 0) { gbstart[NBUCK] = EE; rowstart[NN] = EE; }
}

// ---------------- p2: single-pass bin ----------------
__global__ __launch_bounds__(256) void p2_bin_kernel(const void* __restrict__ eiv,
                                                     const int* __restrict__ gbstart,
                                                     const int* __restrict__ relbase,
                                                     unsigned int* __restrict__ packed) {
    __shared__ int hist[NBUCK];
    __shared__ int basep[NBUCK];
    const int tid = threadIdx.x;
    const int ch = blockIdx.x;
    const int f = detect_i64((const unsigned int*)eiv);
    for (int i = tid; i < NBUCK; i += 256) {
        hist[i] = 0;
        basep[i] = gbstart[i] + relbase[ch * NBUCK + i];
    }
    __syncthreads();
    int beg = ch * CHUNK, end = min(beg + CHUNK, EE);
    for (int e = beg + tid; e < end; e += 256) {
        int s = edge_src(eiv, f, e);
        int d = edge_dst(eiv, f, e);
        int b = d >> BSHIFT;
        int r = atomicAdd(&hist[b], 1);
        packed[basep[b] + r] = (unsigned int)s | ((unsigned int)(d & 127) << 17);
    }
}

// ---------------- p3+gather1 fused ----------------
__global__ __launch_bounds__(256) void p3g1_kernel(const unsigned int* __restrict__ packed,
                                                   const int* __restrict__ gbstart,
                                                   const unsigned short* __restrict__ xb,
                                                   int* __restrict__ rowstart,
                                                   int* __restrict__ eidx,
                                                   unsigned short* __restrict__ agg1) {
    __shared__ int hist[128];
    __shared__ int excl[128];
    __shared__ int sc[128];
    __shared__ int lidx[LDSE];
    const int tid = threadIdx.x;
    const int b = blockIdx.x;
    const int bstart = gbstart[b], bend = gbstart[b + 1];
    const int cnt = bend - bstart;
    if (tid < 128) hist[tid] = 0;
    __syncthreads();
    for (int e = bstart + tid; e < bend; e += 256)
        atomicAdd(&hist[packed[e] >> 17], 1);
    __syncthreads();
    int v = (tid < 128) ? hist[tid] : 0;
    if (tid < 128) sc[tid] = v;
    __syncthreads();
    for (int off = 1; off < 128; off <<= 1) {
        int t = (tid < 128 && tid >= off) ? sc[tid - off] : 0;
        __syncthreads();
        if (tid < 128) sc[tid] += t;
        __syncthreads();
    }
    if (tid < 128) {
        excl[tid] = sc[tid] - v;
        hist[tid] = 0;
        int node = b * 128 + tid;
        if (node < NN) rowstart[node] = bstart + sc[tid] - v;
    }
    __syncthreads();
    const bool inl = (cnt <= LDSE);
    for (int e = bstart + tid; e < bend; e += 256) {
        unsigned int p = packed[e];
        int dl = p >> 17;
        int r = atomicAdd(&hist[dl], 1);
        int pos = excl[dl] + r;
        int sv = (int)(p & 0x1FFFFu);
        eidx[bstart + pos] = sv;
        if (inl) lidx[pos] = sv;
    }
    __syncthreads();
    const int* ep = inl ? (const int*)lidx : (eidx + bstart);
    const int g = tid >> 3, l8 = tid & 7, c = l8 * 8;
    for (int r4 = 0; r4 < 4; r4++) {
        int nl = r4 * 32 + g;
        int node = b * 128 + nl;
        if (node >= NN) continue;
        float acc[8];
        uint4 sv4 = *(const uint4*)(xb + (size_t)node * FF + c);
        {
            const unsigned int* wv = (const unsigned int*)&sv4;
#pragma unroll
            for (int p = 0; p < 4; p++) {
                acc[p * 2] = b2f((unsigned short)(wv[p] & 0xffff));
                acc[p * 2 + 1] = b2f((unsigned short)(wv[p] >> 16));
            }
        }
        auto addv = [&](uint4 u) {
            const unsigned int* wv = (const unsigned int*)&u;
#pragma unroll
            for (int p = 0; p < 4; p++) {
                acc[p * 2] += b2f((unsigned short)(wv[p] & 0xffff));
                acc[p * 2 + 1] += b2f((unsigned short)(wv[p] >> 16));
            }
        };
        int beg2 = excl[nl], cend = beg2 + hist[nl];
        int j = beg2;
        for (; j + 3 < cend; j += 4) {
            int i0 = ep[j], i1 = ep[j + 1], i2 = ep[j + 2], i3 = ep[j + 3];
            uint4 v0 = *(const uint4*)(xb + (size_t)i0 * FF + c);
            uint4 v1 = *(const uint4*)(xb + (size_t)i1 * FF + c);
            uint4 v2 = *(const uint4*)(xb + (size_t)i2 * FF + c);
            uint4 v3 = *(const uint4*)(xb + (size_t)i3 * FF + c);
            addv(v0); addv(v1); addv(v2); addv(v3);
        }
        for (; j < cend; j++)
            addv(*(const uint4*)(xb + (size_t)ep[j] * FF + c));
        uint4 o;
        o.x = pack2(acc[0], acc[1]); o.y = pack2(acc[2], acc[3]);
        o.z = pack2(acc[4], acc[5]); o.w = pack2(acc[6], acc[7]);
        *(uint4*)(agg1 + (size_t)node * FF + c) = o;
    }
}

// ---------------- gather2: uint2 loads (R8 config), fused BN1 ----------------
__global__ __launch_bounds__(256) void gather2_kernel(const unsigned short* __restrict__ h,
                                                      const int* __restrict__ rowstart,
                                                      const int* __restrict__ eidx,
                                                      const float* __restrict__ statsum,
                                                      const float* __restrict__ statsq,
                                                      const float* __restrict__ bng,
                                                      const float* __restrict__ bnb,
                                                      unsigned short* __restrict__ agg2) {
    int node = blockIdx.x * 8 + (threadIdx.x >> 5);
    const int l32 = threadIdx.x & 31;
    const int c = l32 * 4;
    if (node >= NN) return;
    float scl[4], off[4];
#pragma unroll
    for (int k = 0; k < 4; k++) {
        float m = statsum[c + k] * (1.0f / NN);
        float vv = statsq[c + k] * (1.0f / NN) - m * m;
        scl[k] = bng[c + k] * rsqrtf(vv + BN_EPS);
        off[k] = bnb[c + k] - m * scl[k];
    }
    float acc[4] = {0.f, 0.f, 0.f, 0.f};
    auto addv = [&](uint2 u) {
        acc[0] += fmaxf(fmaf(b2f((unsigned short)(u.x & 0xffff)), scl[0], off[0]), 0.f);
        acc[1] += fmaxf(fmaf(b2f((unsigned short)(u.x >> 16)), scl[1], off[1]), 0.f);
        acc[2] += fmaxf(fmaf(b2f((unsigned short)(u.y & 0xffff)), scl[2], off[2]), 0.f);
        acc[3] += fmaxf(fmaf(b2f((unsigned short)(u.y >> 16)), scl[3], off[3]), 0.f);
    };
    addv(*(const uint2*)(h + (size_t)node * HH + c));
    int beg = rowstart[node], end = rowstart[node + 1];
    int j = beg;
    for (; j + 3 < end; j += 4) {
        int i0 = eidx[j], i1 = eidx[j + 1], i2 = eidx[j + 2], i3 = eidx[j + 3];
        uint2 v0 = *(const uint2*)(h + (size_t)i0 * HH + c);
        uint2 v1 = *(const uint2*)(h + (size_t)i1 * HH + c);
        uint2 v2 = *(const uint2*)(h + (size_t)i2 * HH + c);
        uint2 v3 = *(const uint2*)(h + (size_t)i3 * HH + c);
        addv(v0); addv(v1); addv(v2); addv(v3);
    }
    for (; j < end; j++)
        addv(*(const uint2*)(h + (size_t)eidx[j] * HH + c));
    uint2 o;
    o.x = pack2(acc[0], acc[1]);
    o.y = pack2(acc[2], acc[3]);
    *(uint2*)(agg2 + (size_t)node * HH + c) = o;
}

// ---------------- fused MLP: direct-global A/W fragment loads, LDS only for t ----------------
template <int KIN>
__global__ __launch_bounds__(256) void mlp_kernel(const unsigned short* __restrict__ in,
                                                  const unsigned short* __restrict__ wTa,
                                                  const float* __restrict__ ba,
                                                  const unsigned short* __restrict__ wTb,
                                                  const float* __restrict__ bb,
                                                  unsigned short* __restrict__ out,
                                                  float* __restrict__ bnsum,
                                                  float* __restrict__ bnsq) {
    __shared__ __attribute__((aligned(16))) unsigned short sT[MBLK * 136];
    __shared__ float sSt[256];
    __shared__ float sB[256];

    const int tid = threadIdx.x;
    const int wave = tid >> 6, lane = tid & 63;
    const int quad = lane >> 4, l16 = lane & 15;
    const size_t row0 = (size_t)blockIdx.x * MBLK;

    sSt[tid] = 0.f;
    if (tid < 128) sB[tid] = ba[tid];
    else sB[tid] = bb[tid - 128];

    // GEMM1: t = relu(A @ Wa + ba); A and Wa direct from global.
    // (OOB rows past NN read workspace interior -> garbage, but those output
    //  rows are excluded from stats and stores.)
    const unsigned short* Ag = in + row0 * KIN;
    f32x4 acc1[2][8];
#pragma unroll
    for (int t = 0; t < 2; t++)
#pragma unroll
        for (int n = 0; n < 8; n++) acc1[t][n] = 0.f;
#pragma unroll
    for (int ks = 0; ks < KIN / 32; ks++) {
        bf16x8 a0 = *(const bf16x8*)(Ag + (wave * 32 + l16) * KIN + ks * 32 + quad * 8);
        bf16x8 a1 = *(const bf16x8*)(Ag + (wave * 32 + 16 + l16) * KIN + ks * 32 + quad * 8);
#pragma unroll
        for (int nt = 0; nt < 8; nt++) {
            bf16x8 b = *(const bf16x8*)(wTa + (nt * 16 + l16) * KIN + ks * 32 + quad * 8);
            acc1[0][nt] = __builtin_amdgcn_mfma_f32_16x16x32_bf16(a0, b, acc1[0][nt], 0, 0, 0);
            acc1[1][nt] = __builtin_amdgcn_mfma_f32_16x16x32_bf16(a1, b, acc1[1][nt], 0, 0, 0);
        }
    }
    __syncthreads();  // covers sB/sSt init before cross-thread use

    // write t into LDS (stride 136)
#pragma unroll
    for (int nt = 0; nt < 8; nt++) {
        const int col = nt * 16 + l16;
        const float bcol = sB[col];
#pragma unroll
        for (int t = 0; t < 2; t++)
#pragma unroll
            for (int r = 0; r < 4; r++) {
                int rl = wave * 32 + t * 16 + quad * 4 + r;
                sT[rl * 136 + col] = f2bf(fmaxf(acc1[t][nt][r] + bcol, 0.f));
            }
    }
    __syncthreads();

    // GEMM2: h = t @ Wb + bb; Wb direct from global.
    f32x4 acc2[2][8];
#pragma unroll
    for (int t = 0; t < 2; t++)
#pragma unroll
        for (int n = 0; n < 8; n++) acc2[t][n] = 0.f;
#pragma unroll
    for (int ks = 0; ks < 4; ks++) {
        bf16x8 a0 = *(const bf16x8*)(sT + (wave * 32 + l16) * 136 + ks * 32 + quad * 8);
        bf16x8 a1 = *(const bf16x8*)(sT + (wave * 32 + 16 + l16) * 136 + ks * 32 + quad * 8);
#pragma unroll
        for (int nt = 0; nt < 8; nt++) {
            bf16x8 b = *(const bf16x8*)(wTb + (nt * 16 + l16) * 128 + ks * 32 + quad * 8);
            acc2[0][nt] = __builtin_amdgcn_mfma_f32_16x16x32_bf16(a0, b, acc2[0][nt], 0, 0, 0);
            acc2[1][nt] = __builtin_amdgcn_mfma_f32_16x16x32_bf16(a1, b, acc2[1][nt], 0, 0, 0);
        }
    }
    __syncthreads();  // t reads done; reuse sT as output stage

    // epilogue: +bb, BN stats, stage + store
#pragma unroll
    for (int nt = 0; nt < 8; nt++) {
        const int col = nt * 16 + l16;
        const float bcol = sB[128 + col];
        float ls = 0.f, lq = 0.f;
#pragma unroll
        for (int t = 0; t < 2; t++)
#pragma unroll
            for (int r = 0; r < 4; r++) {
                int rl = wave * 32 + t * 16 + quad * 4 + r;
                float v = acc2[t][nt][r] + bcol;
                if (row0 + rl < NN) { ls += v; lq += v * v; }
                sT[rl * 136 + col] = f2bf(v);
            }
        ls += __shfl_down(ls, 32); ls += __shfl_down(ls, 16);
        lq += __shfl_down(lq, 32); lq += __shfl_down(lq, 16);
        if (lane < 16) { atomicAdd(&sSt[col], ls); atomicAdd(&sSt[128 + col], lq); }
    }
    __syncthreads();

    for (int i = tid; i < MBLK * 16; i += 256) {
        int r = i >> 4, c = i & 15;
        if (row0 + r < NN)
            *(uint4*)(out + (row0 + r) * 128 + c * 8) = *(const uint4*)(sT + r * 136 + c * 8);
    }
    if (tid < 128) atomicAdd(&bnsum[tid], sSt[tid]);
    else atomicAdd(&bnsq[tid - 128], sSt[tid]);
}

// ---------------- final: bn2+relu -> latent f32; classifier; direct-global W ----------------
__global__ __launch_bounds__(256) void final_kernel(const unsigned short* __restrict__ h2,
                                                    const float* __restrict__ statsum,
                                                    const float* __restrict__ statsq,
                                                    const float* __restrict__ bng,
                                                    const float* __restrict__ bnb,
                                                    const unsigned short* __restrict__ wTm1,
                                                    const float* __restrict__ mb1,
                                                    const unsigned short* __restrict__ wTm2,
                                                    const float* __restrict__ mb2,
                                                    float* __restrict__ latent,
                                                    float* __restrict__ cls) {
    __shared__ __attribute__((aligned(16))) unsigned short sA[MBLK * 136];
    __shared__ float sBN[256];
    __shared__ float sB1[128];

    const int tid = threadIdx.x;
    const int wave = tid >> 6, lane = tid & 63;
    const int quad = lane >> 4, l16 = lane & 15;
    const size_t row0 = (size_t)blockIdx.x * MBLK;

    if (tid < 128) {
        float mean = statsum[tid] * (1.0f / NN);
        float var = statsq[tid] * (1.0f / NN) - mean * mean;
        float sc = bng[tid] * rsqrtf(var + BN_EPS);
        sBN[tid] = sc;
        sBN[128 + tid] = bnb[tid] - mean * sc;
        sB1[tid] = mb1[tid];
    }
    __syncthreads();

    // stage lat = bnrelu(h2) into sA; write latent f32
    for (int i = tid; i < MBLK * 16; i += 256) {
        int r = i >> 4, c = i & 15;
        bool live = (row0 + r < NN);
        uint4 hv = {0u, 0u, 0u, 0u};
        if (live) hv = *(const uint4*)(h2 + (row0 + r) * 128 + c * 8);
        const unsigned int* wv = (const unsigned int*)&hv;
        float vs[8];
#pragma unroll
        for (int p = 0; p < 4; p++) {
            int cc = c * 8 + p * 2;
            vs[p * 2]     = fmaxf(fmaf(b2f((unsigned short)(wv[p] & 0xffff)), sBN[cc], sBN[128 + cc]), 0.f);
            vs[p * 2 + 1] = fmaxf(fmaf(b2f((unsigned short)(wv[p] >> 16)), sBN[cc + 1], sBN[129 + cc]), 0.f);
        }
        if (live) {
            float4 f0 = {vs[0], vs[1], vs[2], vs[3]};
            float4 f1 = {vs[4], vs[5], vs[6], vs[7]};
            float* lp = latent + (row0 + r) * 128 + c * 8;
            *(float4*)lp = f0;
            *(float4*)(lp + 4) = f1;
        }
        uint4 o;
        o.x = pack2(vs[0], vs[1]); o.y = pack2(vs[2], vs[3]);
        o.z = pack2(vs[4], vs[5]); o.w = pack2(vs[6], vs[7]);
        *(uint4*)(sA + r * 136 + c * 8) = o;
    }
    __syncthreads();

    // GEMM1: m = relu(lat @ mw1 + mb1), W direct global
    f32x4 acc1[2][8];
#pragma unroll
    for (int t = 0; t < 2; t++)
#pragma unroll
        for (int n = 0; n < 8; n++) acc1[t][n] = 0.f;
#pragma unroll
    for (int ks = 0; ks < 4; ks++) {
        bf16x8 av0 = *(const bf16x8*)(sA + (wave * 32 + l16) * 136 + ks * 32 + quad * 8);
        bf16x8 av1 = *(const bf16x8*)(sA + (wave * 32 + 16 + l16) * 136 + ks * 32 + quad * 8);
#pragma unroll
        for (int nt = 0; nt < 8; nt++) {
            bf16x8 b = *(const bf16x8*)(wTm1 + (nt * 16 + l16) * 128 + ks * 32 + quad * 8);
            acc1[0][nt] = __builtin_amdgcn_mfma_f32_16x16x32_bf16(av0, b, acc1[0][nt], 0, 0, 0);
            acc1[1][nt] = __builtin_amdgcn_mfma_f32_16x16x32_bf16(av1, b, acc1[1][nt], 0, 0, 0);
        }
    }
    __syncthreads();

    // write m into sA
#pragma unroll
    for (int nt = 0; nt < 8; nt++) {
        const int col = nt * 16 + l16;
        const float bcol = sB1[col];
#pragma unroll
        for (int t = 0; t < 2; t++)
#pragma unroll
            for (int r = 0; r < 4; r++) {
                int rl = wave * 32 + t * 16 + quad * 4 + r;
                sA[rl * 136 + col] = f2bf(fmaxf(acc1[t][nt][r] + bcol, 0.f));
            }
    }
    __syncthreads();

    // GEMM2: cls = m @ mw2 + mb2, W direct global
    f32x4 acc2[2];
    acc2[0] = 0.f; acc2[1] = 0.f;
#pragma unroll
    for (int ks = 0; ks < 4; ks++) {
        bf16x8 av0 = *(const bf16x8*)(sA + (wave * 32 + l16) * 136 + ks * 32 + quad * 8);
        bf16x8 av1 = *(const bf16x8*)(sA + (wave * 32 + 16 + l16) * 136 + ks * 32 + quad * 8);
        bf16x8 b = *(const bf16x8*)(wTm2 + l16 * 128 + ks * 32 + quad * 8);
        acc2[0] = __builtin_amdgcn_mfma_f32_16x16x32_bf16(av0, b, acc2[0], 0, 0, 0);
        acc2[1] = __builtin_amdgcn_mfma_f32_16x16x32_bf16(av1, b, acc2[1], 0, 0, 0);
    }
    __syncthreads();

    float* sOf = (float*)sA;
    if (l16 < CC) {
        const float bc = mb2[l16];
#pragma unroll
        for (int t = 0; t < 2; t++)
#pragma unroll
            for (int r = 0; r < 4; r++) {
                int rl = wave * 32 + t * 16 + quad * 4 + r;
                sOf[rl * CC + l16] = acc2[t][r] + bc;
            }
    }
    __syncthreads();
    for (int i = tid; i < MBLK * CC; i += 256) {
        long long gi = (long long)row0 * CC + i;
        if (gi < (long long)NN * CC) cls[gi] = sOf[i];
    }
}

extern "C" void kernel_launch(void* const* d_in, const int* in_sizes, int n_in,
                              void* d_out, int out_size, void* d_ws, size_t ws_size,
                              hipStream_t stream) {
    const float* x   = (const float*)d_in[0];
    const void* ei   = d_in[1];
    const float* w1a = (const float*)d_in[2];
    const float* b1a = (const float*)d_in[3];
    const float* w1b = (const float*)d_in[4];
    const float* b1b = (const float*)d_in[5];
    const float* w2a = (const float*)d_in[6];
    const float* b2a = (const float*)d_in[7];
    const float* w2b = (const float*)d_in[8];
    const float* b2b = (const float*)d_in[9];
    const float* bn1g = (const float*)d_in[10];
    const float* bn1b = (const float*)d_in[11];
    const float* bn2g = (const float*)d_in[12];
    const float* bn2b = (const float*)d_in[13];
    const float* mw1 = (const float*)d_in[14];
    const float* mb1 = (const float*)d_in[15];
    const float* mw2 = (const float*)d_in[16];
    const float* mb2 = (const float*)d_in[17];
    float* out = (float*)d_out;

    char* w = (char*)d_ws;
    unsigned short* xb   = (unsigned short*)w;  w += (size_t)NN * FF * 2;
    unsigned short* agg1 = (unsigned short*)w;  w += (size_t)NN * FF * 2;
    unsigned short* h    = (unsigned short*)w;  w += (size_t)NN * HH * 2;  // h1 then h2
    unsigned short* agg2 = (unsigned short*)w;  w += (size_t)NN * HH * 2;
    float* stats = (float*)w;                   w += 1024 * 4;
    int* eidx = (int*)w;                        w += (size_t)EE * 4;
    unsigned int* packed = (unsigned int*)w;    w += (size_t)EE * 4;
    int* rowstart = (int*)w;                    w += (NN + 2) * 4;
    int* gbcount = (int*)w;                     w += (NBUCK + 2) * 4;
    int* gbstart = (int*)w;                     w += (NBUCK + 2) * 4;
    int* donecnt = (int*)w;                     w += 16;
    int* chunkhist = (int*)w;                   w += (size_t)NB_CH * NBUCK * 4;
    unsigned short* wt1a = (unsigned short*)w;  w += 8192 * 2;
    unsigned short* wt1b = (unsigned short*)w;  w += 16384 * 2;
    unsigned short* wt2a = (unsigned short*)w;  w += 16384 * 2;
    unsigned short* wt2b = (unsigned short*)w;  w += 16384 * 2;
    unsigned short* wtm1 = (unsigned short*)w;  w += 16384 * 2;
    unsigned short* wtm2 = (unsigned short*)w;  w += 2048 * 2;

    cvtprep_kernel<<<NB_CVT + TWB + NB_CH, 256, 0, stream>>>(
        x, xb, w1a, w1b, w2a, w2b, mw1, mw2,
        wt1a, wt1b, wt2a, wt2b, wtm1, wtm2, stats, donecnt, ei, chunkhist);

    chunkscan_kernel<<<NBUCK, 128, 0, stream>>>(chunkhist, gbcount, gbstart, rowstart, donecnt);
    p2_bin_kernel<<<NB_CH, 256, 0, stream>>>(ei, gbstart, chunkhist, packed);

    p3g1_kernel<<<NBUCK, 256, 0, stream>>>(packed, gbstart, xb, rowstart, eidx, agg1);

    mlp_kernel<FF><<<NBLK_LIN, 256, 0, stream>>>(agg1, wt1a, b1a, wt1b, b1b, h, stats, stats + 128);

    gather2_kernel<<<(NN + 7) / 8, 256, 0, stream>>>(
        h, rowstart, eidx, stats, stats + 128, bn1g, bn1b, agg2);
    mlp_kernel<HH><<<NBLK_LIN, 256, 0, stream>>>(agg2, wt2a, b2a, wt2b, b2b, h, stats + 256, stats + 384);

    final_kernel<<<NBLK_LIN, 256, 0, stream>>>(
        h, stats + 256, stats + 384, bn2g, bn2b,
        wtm1, mb1, wtm2, mb2, out, out + (size_t)NN * HH);
}

// Round 11
// 428.594 us; speedup vs baseline: 1.1206x; 1.1206x over previous
//
#include <hip/hip_runtime.h>
#include <cstdint>

// GIN model: N=100000, F=64, H=128, C=10, E=1600000.
// R11: revert R10's direct-global MFMA fragments (uncoalesced lane-strided W reads
// -> 200cyc L2 stalls, MfmaUtil 3.5%). Back to R8 LDS-staged mlp/final + uint2
// gather2. Keep merged chunkscan+bscan (last-block pattern). 8 dispatches.

#define NN 100000
#define FF 64
#define HH 128
#define CC 10
#define EE 1600000
#define BN_EPS 1e-5f
#define MBLK 128
#define NBLK_LIN ((NN + MBLK - 1) / MBLK)  // 782
#define BSHIFT 7
#define NBUCK ((NN + 127) / 128)           // 782
#define CHUNK 16384
#define NB_CH ((EE + CHUNK - 1) / CHUNK)   // 98
#define NB_CVT 3125                        // 100000*64/8/256 exactly
#define TW (8192 + 4 * 16384 + 2048)
#define TWB ((TW + 255) / 256)
#define LDSE 3072

typedef __attribute__((ext_vector_type(8))) short bf16x8;
typedef __attribute__((ext_vector_type(4))) float f32x4;

__device__ inline unsigned short f2bf(float f) {
    unsigned int u = __float_as_uint(f);
    unsigned int r = (u + 0x7fffu + ((u >> 16) & 1u)) >> 16;
    return (unsigned short)r;
}
__device__ inline float b2f(unsigned short h) {
    return __uint_as_float(((unsigned int)h) << 16);
}
__device__ inline unsigned int pack2(float a, float b) {
    return (unsigned int)f2bf(a) | ((unsigned int)f2bf(b) << 16);
}
__device__ inline int detect_i64(const unsigned int* e) {
    return (e[1] | e[3] | e[5] | e[7]) == 0u;
}
__device__ inline int edge_dst(const void* eiv, int f, int e) {
    return f ? (int)((const long long*)eiv)[EE + e] : ((const int*)eiv)[EE + e];
}
__device__ inline int edge_src(const void* eiv, int f, int e) {
    return f ? (int)((const long long*)eiv)[e] : ((const int*)eiv)[e];
}

// ---------------- prep: x->bf16, weight transpose, zeroing, per-chunk dst hist ----------------
__global__ __launch_bounds__(256) void cvtprep_kernel(
    const float* __restrict__ x, unsigned short* __restrict__ xb,
    const float* __restrict__ w1a, const float* __restrict__ w1b,
    const float* __restrict__ w2a, const float* __restrict__ w2b,
    const float* __restrict__ mw1, const float* __restrict__ mw2,
    unsigned short* __restrict__ wt1a, unsigned short* __restrict__ wt1b,
    unsigned short* __restrict__ wt2a, unsigned short* __restrict__ wt2b,
    unsigned short* __restrict__ wtm1, unsigned short* __restrict__ wtm2,
    float* __restrict__ stats, int* __restrict__ donecnt,
    const void* __restrict__ eiv, int* __restrict__ chunkhist) {
    __shared__ int hist[NBUCK];
    const int tid = threadIdx.x;
    const int b = blockIdx.x;
    if (b == 0) {
        for (int i = tid; i < 512; i += 256) stats[i] = 0.f;
        if (tid == 0) donecnt[0] = 0;
    }
    if (b < NB_CVT) {
        int i = b * 256 + tid;
        float4 a = ((const float4*)x)[i * 2];
        float4 c = ((const float4*)x)[i * 2 + 1];
        uint4 o;
        o.x = pack2(a.x, a.y); o.y = pack2(a.z, a.w);
        o.z = pack2(c.x, c.y); o.w = pack2(c.z, c.w);
        ((uint4*)xb)[i] = o;
        return;
    }
    if (b < NB_CVT + TWB) {
        int idx = (b - NB_CVT) * 256 + tid;
        if (idx < 8192) {
            int k = idx >> 7, n = idx & 127;
            wt1a[n * 64 + k] = f2bf(w1a[idx]);
        } else if (idx < 8192 + 16384) {
            int t = idx - 8192; int k = t >> 7, n = t & 127;
            wt1b[n * 128 + k] = f2bf(w1b[t]);
        } else if (idx < 8192 + 2 * 16384) {
            int t = idx - (8192 + 16384); int k = t >> 7, n = t & 127;
            wt2a[n * 128 + k] = f2bf(w2a[t]);
        } else if (idx < 8192 + 3 * 16384) {
            int t = idx - (8192 + 2 * 16384); int k = t >> 7, n = t & 127;
            wt2b[n * 128 + k] = f2bf(w2b[t]);
        } else if (idx < 8192 + 4 * 16384) {
            int t = idx - (8192 + 3 * 16384); int k = t >> 7, n = t & 127;
            wtm1[n * 128 + k] = f2bf(mw1[t]);
        } else if (idx < TW) {
            int t = idx - (8192 + 4 * 16384); int n = t & 15, k = t >> 4;
            wtm2[n * 128 + k] = (n < CC) ? f2bf(mw2[k * CC + n]) : (unsigned short)0;
        }
        return;
    }
    const int ch = b - NB_CVT - TWB;
    const int f = detect_i64((const unsigned int*)eiv);
    for (int i = tid; i < NBUCK; i += 256) hist[i] = 0;
    __syncthreads();
    int beg = ch * CHUNK, end = min(beg + CHUNK, EE);
    for (int e = beg + tid; e < end; e += 256)
        atomicAdd(&hist[edge_dst(eiv, f, e) >> BSHIFT], 1);
    __syncthreads();
    for (int i = tid; i < NBUCK; i += 256) chunkhist[ch * NBUCK + i] = hist[i];
}

// ---------------- chunkscan (+ bucket scan in last block) ----------------
__global__ __launch_bounds__(128) void chunkscan_kernel(int* __restrict__ chunkhist,
                                                        int* __restrict__ gbcount,
                                                        int* __restrict__ gbstart,
                                                        int* __restrict__ rowstart,
                                                        int* __restrict__ donecnt) {
    __shared__ int s[128];
    __shared__ int isLast;
    const int b = blockIdx.x, tid = threadIdx.x;
    int v = (tid < NB_CH) ? chunkhist[tid * NBUCK + b] : 0;
    s[tid] = v;
    __syncthreads();
    for (int off = 1; off < 128; off <<= 1) {
        int t = (tid >= off) ? s[tid - off] : 0;
        __syncthreads();
        s[tid] += t;
        __syncthreads();
    }
    if (tid < NB_CH) chunkhist[tid * NBUCK + b] = s[tid] - v;
    if (tid == 127) gbcount[b] = s[127];
    __threadfence();
    __syncthreads();
    if (tid == 0) isLast = (atomicAdd(donecnt, 1) == NBUCK - 1) ? 1 : 0;
    __syncthreads();
    if (!isLast) return;
    __threadfence();
    int carry = 0;
    for (int c0 = 0; c0 < NBUCK; c0 += 128) {
        int vv = (c0 + tid < NBUCK) ? gbcount[c0 + tid] : 0;
        __syncthreads();
        s[tid] = vv;
        __syncthreads();
        for (int off = 1; off < 128; off <<= 1) {
            int t = (tid >= off) ? s[tid - off] : 0;
            __syncthreads();
            s[tid] += t;
            __syncthreads();
        }
        if (c0 + tid < NBUCK) gbstart[c0 + tid] = carry + s[tid] - vv;
        carry += s[127];
        __syncthreads();
    }
    if (tid == 0) { gbstart[NBUCK] = EE; rowstart[NN] = EE; }
}

// ---------------- p2: single-pass bin ----------------
__global__ __launch_bounds__(256) void p2_bin_kernel(const void* __restrict__ eiv,
                                                     const int* __restrict__ gbstart,
                                                     const int* __restrict__ relbase,
                                                     unsigned int* __restrict__ packed) {
    __shared__ int hist[NBUCK];
    __shared__ int basep[NBUCK];
    const int tid = threadIdx.x;
    const int ch = blockIdx.x;
    const int f = detect_i64((const unsigned int*)eiv);
    for (int i = tid; i < NBUCK; i += 256) {
        hist[i] = 0;
        basep[i] = gbstart[i] + relbase[ch * NBUCK + i];
    }
    __syncthreads();
    int beg = ch * CHUNK, end = min(beg + CHUNK, EE);
    for (int e = beg + tid; e < end; e += 256) {
        int s = edge_src(eiv, f, e);
        int d = edge_dst(eiv, f, e);
        int b = d >> BSHIFT;
        int r = atomicAdd(&hist[b], 1);
        packed[basep[b] + r] = (unsigned int)s | ((unsigned int)(d & 127) << 17);
    }
}

// ---------------- p3+gather1 fused ----------------
__global__ __launch_bounds__(256) void p3g1_kernel(const unsigned int* __restrict__ packed,
                                                   const int* __restrict__ gbstart,
                                                   const unsigned short* __restrict__ xb,
                                                   int* __restrict__ rowstart,
                                                   int* __restrict__ eidx,
                                                   unsigned short* __restrict__ agg1) {
    __shared__ int hist[128];
    __shared__ int excl[128];
    __shared__ int sc[128];
    __shared__ int lidx[LDSE];
    const int tid = threadIdx.x;
    const int b = blockIdx.x;
    const int bstart = gbstart[b], bend = gbstart[b + 1];
    const int cnt = bend - bstart;
    if (tid < 128) hist[tid] = 0;
    __syncthreads();
    for (int e = bstart + tid; e < bend; e += 256)
        atomicAdd(&hist[packed[e] >> 17], 1);
    __syncthreads();
    int v = (tid < 128) ? hist[tid] : 0;
    if (tid < 128) sc[tid] = v;
    __syncthreads();
    for (int off = 1; off < 128; off <<= 1) {
        int t = (tid < 128 && tid >= off) ? sc[tid - off] : 0;
        __syncthreads();
        if (tid < 128) sc[tid] += t;
        __syncthreads();
    }
    if (tid < 128) {
        excl[tid] = sc[tid] - v;
        hist[tid] = 0;
        int node = b * 128 + tid;
        if (node < NN) rowstart[node] = bstart + sc[tid] - v;
    }
    __syncthreads();
    const bool inl = (cnt <= LDSE);
    for (int e = bstart + tid; e < bend; e += 256) {
        unsigned int p = packed[e];
        int dl = p >> 17;
        int r = atomicAdd(&hist[dl], 1);
        int pos = excl[dl] + r;
        int sv = (int)(p & 0x1FFFFu);
        eidx[bstart + pos] = sv;
        if (inl) lidx[pos] = sv;
    }
    __syncthreads();
    const int* ep = inl ? (const int*)lidx : (eidx + bstart);
    const int g = tid >> 3, l8 = tid & 7, c = l8 * 8;
    for (int r4 = 0; r4 < 4; r4++) {
        int nl = r4 * 32 + g;
        int node = b * 128 + nl;
        if (node >= NN) continue;
        float acc[8];
        uint4 sv4 = *(const uint4*)(xb + (size_t)node * FF + c);
        {
            const unsigned int* wv = (const unsigned int*)&sv4;
#pragma unroll
            for (int p = 0; p < 4; p++) {
                acc[p * 2] = b2f((unsigned short)(wv[p] & 0xffff));
                acc[p * 2 + 1] = b2f((unsigned short)(wv[p] >> 16));
            }
        }
        auto addv = [&](uint4 u) {
            const unsigned int* wv = (const unsigned int*)&u;
#pragma unroll
            for (int p = 0; p < 4; p++) {
                acc[p * 2] += b2f((unsigned short)(wv[p] & 0xffff));
                acc[p * 2 + 1] += b2f((unsigned short)(wv[p] >> 16));
            }
        };
        int beg2 = excl[nl], cend = beg2 + hist[nl];
        int j = beg2;
        for (; j + 3 < cend; j += 4) {
            int i0 = ep[j], i1 = ep[j + 1], i2 = ep[j + 2], i3 = ep[j + 3];
            uint4 v0 = *(const uint4*)(xb + (size_t)i0 * FF + c);
            uint4 v1 = *(const uint4*)(xb + (size_t)i1 * FF + c);
            uint4 v2 = *(const uint4*)(xb + (size_t)i2 * FF + c);
            uint4 v3 = *(const uint4*)(xb + (size_t)i3 * FF + c);
            addv(v0); addv(v1); addv(v2); addv(v3);
        }
        for (; j < cend; j++)
            addv(*(const uint4*)(xb + (size_t)ep[j] * FF + c));
        uint4 o;
        o.x = pack2(acc[0], acc[1]); o.y = pack2(acc[2], acc[3]);
        o.z = pack2(acc[4], acc[5]); o.w = pack2(acc[6], acc[7]);
        *(uint4*)(agg1 + (size_t)node * FF + c) = o;
    }
}

// ---------------- gather2: uint2 loads, fused BN1 (R8 config) ----------------
__global__ __launch_bounds__(256) void gather2_kernel(const unsigned short* __restrict__ h,
                                                      const int* __restrict__ rowstart,
                                                      const int* __restrict__ eidx,
                                                      const float* __restrict__ statsum,
                                                      const float* __restrict__ statsq,
                                                      const float* __restrict__ bng,
                                                      const float* __restrict__ bnb,
                                                      unsigned short* __restrict__ agg2) {
    int node = blockIdx.x * 8 + (threadIdx.x >> 5);
    const int l32 = threadIdx.x & 31;
    const int c = l32 * 4;
    if (node >= NN) return;
    float scl[4], off[4];
#pragma unroll
    for (int k = 0; k < 4; k++) {
        float m = statsum[c + k] * (1.0f / NN);
        float vv = statsq[c + k] * (1.0f / NN) - m * m;
        scl[k] = bng[c + k] * rsqrtf(vv + BN_EPS);
        off[k] = bnb[c + k] - m * scl[k];
    }
    float acc[4] = {0.f, 0.f, 0.f, 0.f};
    auto addv = [&](uint2 u) {
        acc[0] += fmaxf(fmaf(b2f((unsigned short)(u.x & 0xffff)), scl[0], off[0]), 0.f);
        acc[1] += fmaxf(fmaf(b2f((unsigned short)(u.x >> 16)), scl[1], off[1]), 0.f);
        acc[2] += fmaxf(fmaf(b2f((unsigned short)(u.y & 0xffff)), scl[2], off[2]), 0.f);
        acc[3] += fmaxf(fmaf(b2f((unsigned short)(u.y >> 16)), scl[3], off[3]), 0.f);
    };
    addv(*(const uint2*)(h + (size_t)node * HH + c));
    int beg = rowstart[node], end = rowstart[node + 1];
    int j = beg;
    for (; j + 3 < end; j += 4) {
        int i0 = eidx[j], i1 = eidx[j + 1], i2 = eidx[j + 2], i3 = eidx[j + 3];
        uint2 v0 = *(const uint2*)(h + (size_t)i0 * HH + c);
        uint2 v1 = *(const uint2*)(h + (size_t)i1 * HH + c);
        uint2 v2 = *(const uint2*)(h + (size_t)i2 * HH + c);
        uint2 v3 = *(const uint2*)(h + (size_t)i3 * HH + c);
        addv(v0); addv(v1); addv(v2); addv(v3);
    }
    for (; j < end; j++)
        addv(*(const uint2*)(h + (size_t)eidx[j] * HH + c));
    uint2 o;
    o.x = pack2(acc[0], acc[1]);
    o.y = pack2(acc[2], acc[3]);
    *(uint2*)(agg2 + (size_t)node * HH + c) = o;
}

// ---------------- fused MLP (R8: LDS-staged A and W) ----------------
template <int KIN>
__global__ __launch_bounds__(256) void mlp_kernel(const unsigned short* __restrict__ in,
                                                  const unsigned short* __restrict__ wTa,
                                                  const float* __restrict__ ba,
                                                  const unsigned short* __restrict__ wTb,
                                                  const float* __restrict__ bb,
                                                  unsigned short* __restrict__ out,
                                                  float* __restrict__ bnsum,
                                                  float* __restrict__ bnsq) {
    constexpr int KLDA = KIN + 8;
    constexpr int CH = KIN / 8;
    __shared__ __attribute__((aligned(16))) unsigned short sA[MBLK * 136];
    __shared__ __attribute__((aligned(16))) unsigned short sW[128 * 136];
    __shared__ float sSt[256];
    __shared__ float sB[256];

    const int tid = threadIdx.x;
    const int wave = tid >> 6, lane = tid & 63;
    const int quad = lane >> 4, l16 = lane & 15;
    const long long row0 = (long long)blockIdx.x * MBLK;

    sSt[tid] = 0.f;
    if (tid < 128) sB[tid] = ba[tid];
    else sB[tid] = bb[tid - 128];

    for (int i = tid; i < 128 * CH; i += 256)
        *(uint4*)(sW + (i / CH) * KLDA + (i % CH) * 8) = ((const uint4*)wTa)[i];
    for (int i = tid; i < MBLK * CH; i += 256) {
        int r = i / CH, c = i % CH;
        uint4 v = {0u, 0u, 0u, 0u};
        if (row0 + r < NN) v = *(const uint4*)(in + (row0 + r) * KIN + c * 8);
        *(uint4*)(sA + r * KLDA + c * 8) = v;
    }
    __syncthreads();

    f32x4 acc1[2][8];
#pragma unroll
    for (int t = 0; t < 2; t++)
#pragma unroll
        for (int n = 0; n < 8; n++) acc1[t][n] = 0.f;
#pragma unroll
    for (int ks = 0; ks < KIN / 32; ks++) {
        bf16x8 a0 = *(const bf16x8*)(sA + (wave * 32 + l16) * KLDA + ks * 32 + quad * 8);
        bf16x8 a1 = *(const bf16x8*)(sA + (wave * 32 + 16 + l16) * KLDA + ks * 32 + quad * 8);
#pragma unroll
        for (int nt = 0; nt < 8; nt++) {
            bf16x8 b = *(const bf16x8*)(sW + (nt * 16 + l16) * KLDA + ks * 32 + quad * 8);
            acc1[0][nt] = __builtin_amdgcn_mfma_f32_16x16x32_bf16(a0, b, acc1[0][nt], 0, 0, 0);
            acc1[1][nt] = __builtin_amdgcn_mfma_f32_16x16x32_bf16(a1, b, acc1[1][nt], 0, 0, 0);
        }
    }
    __syncthreads();

#pragma unroll
    for (int nt = 0; nt < 8; nt++) {
        const int col = nt * 16 + l16;
        const float bcol = sB[col];
#pragma unroll
        for (int t = 0; t < 2; t++)
#pragma unroll
            for (int r = 0; r < 4; r++) {
                int rl = wave * 32 + t * 16 + quad * 4 + r;
                sA[rl * 136 + col] = f2bf(fmaxf(acc1[t][nt][r] + bcol, 0.f));
            }
    }
    for (int i = tid; i < 128 * 16; i += 256)
        *(uint4*)(sW + (i >> 4) * 136 + (i & 15) * 8) = ((const uint4*)wTb)[i];
    __syncthreads();

    f32x4 acc2[2][8];
#pragma unroll
    for (int t = 0; t < 2; t++)
#pragma unroll
        for (int n = 0; n < 8; n++) acc2[t][n] = 0.f;
#pragma unroll
    for (int ks = 0; ks < 4; ks++) {
        bf16x8 a0 = *(const bf16x8*)(sA + (wave * 32 + l16) * 136 + ks * 32 + quad * 8);
        bf16x8 a1 = *(const bf16x8*)(sA + (wave * 32 + 16 + l16) * 136 + ks * 32 + quad * 8);
#pragma unroll
        for (int nt = 0; nt < 8; nt++) {
            bf16x8 b = *(const bf16x8*)(sW + (nt * 16 + l16) * 136 + ks * 32 + quad * 8);
            acc2[0][nt] = __builtin_amdgcn_mfma_f32_16x16x32_bf16(a0, b, acc2[0][nt], 0, 0, 0);
            acc2[1][nt] = __builtin_amdgcn_mfma_f32_16x16x32_bf16(a1, b, acc2[1][nt], 0, 0, 0);
        }
    }
    __syncthreads();

#pragma unroll
    for (int nt = 0; nt < 8; nt++) {
        const int col = nt * 16 + l16;
        const float bcol = sB[128 + col];
        float ls = 0.f, lq = 0.f;
#pragma unroll
        for (int t = 0; t < 2; t++)
#pragma unroll
            for (int r = 0; r < 4; r++) {
                int rl = wave * 32 + t * 16 + quad * 4 + r;
                float v = acc2[t][nt][r] + bcol;
                if (row0 + rl < NN) { ls += v; lq += v * v; }
                sA[rl * 136 + col] = f2bf(v);
            }
        ls += __shfl_down(ls, 32); ls += __shfl_down(ls, 16);
        lq += __shfl_down(lq, 32); lq += __shfl_down(lq, 16);
        if (lane < 16) { atomicAdd(&sSt[col], ls); atomicAdd(&sSt[128 + col], lq); }
    }
    __syncthreads();

    for (int i = tid; i < MBLK * 16; i += 256) {
        int r = i >> 4, c = i & 15;
        if (row0 + r < NN)
            *(uint4*)(out + (row0 + r) * 128 + c * 8) = *(const uint4*)(sA + r * 136 + c * 8);
    }
    if (tid < 128) atomicAdd(&bnsum[tid], sSt[tid]);
    else atomicAdd(&bnsq[tid - 128], sSt[tid]);
}

// ---------------- final (R8: LDS-staged) ----------------
__global__ __launch_bounds__(256) void final_kernel(const unsigned short* __restrict__ h2,
                                                    const float* __restrict__ statsum,
                                                    const float* __restrict__ statsq,
                                                    const float* __restrict__ bng,
                                                    const float* __restrict__ bnb,
                                                    const unsigned short* __restrict__ wTm1,
                                                    const float* __restrict__ mb1,
                                                    const unsigned short* __restrict__ wTm2,
                                                    const float* __restrict__ mb2,
                                                    float* __restrict__ latent,
                                                    float* __restrict__ cls) {
    __shared__ __attribute__((aligned(16))) unsigned short sA[MBLK * 136];
    __shared__ __attribute__((aligned(16))) unsigned short sW[128 * 136];
    __shared__ float sBN[256];
    __shared__ float sB1[128];

    const int tid = threadIdx.x;
    const int wave = tid >> 6, lane = tid & 63;
    const int quad = lane >> 4, l16 = lane & 15;
    const long long row0 = (long long)blockIdx.x * MBLK;

    if (tid < 128) {
        float mean = statsum[tid] * (1.0f / NN);
        float var = statsq[tid] * (1.0f / NN) - mean * mean;
        float sc = bng[tid] * rsqrtf(var + BN_EPS);
        sBN[tid] = sc;
        sBN[128 + tid] = bnb[tid] - mean * sc;
        sB1[tid] = mb1[tid];
    }
    for (int i = tid; i < 128 * 16; i += 256)
        *(uint4*)(sW + (i >> 4) * 136 + (i & 15) * 8) = ((const uint4*)wTm1)[i];
    __syncthreads();

    for (int i = tid; i < MBLK * 16; i += 256) {
        int r = i >> 4, c = i & 15;
        bool live = (row0 + r < NN);
        uint4 hv = {0u, 0u, 0u, 0u};
        if (live) hv = *(const uint4*)(h2 + (row0 + r) * 128 + c * 8);
        const unsigned int* wv = (const unsigned int*)&hv;
        float vs[8];
#pragma unroll
        for (int p = 0; p < 4; p++) {
            int cc = c * 8 + p * 2;
            vs[p * 2]     = fmaxf(fmaf(b2f((unsigned short)(wv[p] & 0xffff)), sBN[cc], sBN[128 + cc]), 0.f);
            vs[p * 2 + 1] = fmaxf(fmaf(b2f((unsigned short)(wv[p] >> 16)), sBN[cc + 1], sBN[129 + cc]), 0.f);
        }
        if (live) {
            float4 f0 = {vs[0], vs[1], vs[2], vs[3]};
            float4 f1 = {vs[4], vs[5], vs[6], vs[7]};
            float* lp = latent + (row0 + r) * 128 + c * 8;
            *(float4*)lp = f0;
            *(float4*)(lp + 4) = f1;
        }
        uint4 o;
        o.x = pack2(vs[0], vs[1]); o.y = pack2(vs[2], vs[3]);
        o.z = pack2(vs[4], vs[5]); o.w = pack2(vs[6], vs[7]);
        *(uint4*)(sA + r * 136 + c * 8) = o;
    }
    __syncthreads();

    f32x4 acc1[2][8];
#pragma unroll
    for (int t = 0; t < 2; t++)
#pragma unroll
        for (int n = 0; n < 8; n++) acc1[t][n] = 0.f;
#pragma unroll
    for (int ks = 0; ks < 4; ks++) {
        bf16x8 av0 = *(const bf16x8*)(sA + (wave * 32 + l16) * 136 + ks * 32 + quad * 8);
        bf16x8 av1 = *(const bf16x8*)(sA + (wave * 32 + 16 + l16) * 136 + ks * 32 + quad * 8);
#pragma unroll
        for (int nt = 0; nt < 8; nt++) {
            bf16x8 b = *(const bf16x8*)(sW + (nt * 16 + l16) * 136 + ks * 32 + quad * 8);
            acc1[0][nt] = __builtin_amdgcn_mfma_f32_16x16x32_bf16(av0, b, acc1[0][nt], 0, 0, 0);
            acc1[1][nt] = __builtin_amdgcn_mfma_f32_16x16x32_bf16(av1, b, acc1[1][nt], 0, 0, 0);
        }
    }
    __syncthreads();

#pragma unroll
    for (int nt = 0; nt < 8; nt++) {
        const int col = nt * 16 + l16;
        const float bcol = sB1[col];
#pragma unroll
        for (int t = 0; t < 2; t++)
#pragma unroll
            for (int r = 0; r < 4; r++) {
                int rl = wave * 32 + t * 16 + quad * 4 + r;
                sA[rl * 136 + col] = f2bf(fmaxf(acc1[t][nt][r] + bcol, 0.f));
            }
    }
    if (tid < 256)
        *(uint4*)(sW + (tid >> 4) * 136 + (tid & 15) * 8) = ((const uint4*)wTm2)[tid];
    __syncthreads();

    f32x4 acc2[2];
    acc2[0] = 0.f; acc2[1] = 0.f;
#pragma unroll
    for (int ks = 0; ks < 4; ks++) {
        bf16x8 av0 = *(const bf16x8*)(sA + (wave * 32 + l16) * 136 + ks * 32 + quad * 8);
        bf16x8 av1 = *(const bf16x8*)(sA + (wave * 32 + 16 + l16) * 136 + ks * 32 + quad * 8);
        bf16x8 b = *(const bf16x8*)(sW + l16 * 136 + ks * 32 + quad * 8);
        acc2[0] = __builtin_amdgcn_mfma_f32_16x16x32_bf16(av0, b, acc2[0], 0, 0, 0);
        acc2[1] = __builtin_amdgcn_mfma_f32_16x16x32_bf16(av1, b, acc2[1], 0, 0, 0);
    }
    __syncthreads();

    float* sOf = (float*)sA;
    if (l16 < CC) {
        const float bc = mb2[l16];
#pragma unroll
        for (int t = 0; t < 2; t++)
#pragma unroll
            for (int r = 0; r < 4; r++) {
                int rl = wave * 32 + t * 16 + quad * 4 + r;
                sOf[rl * CC + l16] = acc2[t][r] + bc;
            }
    }
    __syncthreads();
    for (int i = tid; i < MBLK * CC; i += 256) {
        long long gi = row0 * CC + i;
        if (gi < (long long)NN * CC) cls[gi] = sOf[i];
    }
}

extern "C" void kernel_launch(void* const* d_in, const int* in_sizes, int n_in,
                              void* d_out, int out_size, void* d_ws, size_t ws_size,
                              hipStream_t stream) {
    const float* x   = (const float*)d_in[0];
    const void* ei   = d_in[1];
    const float* w1a = (const float*)d_in[2];
    const float* b1a = (const float*)d_in[3];
    const float* w1b = (const float*)d_in[4];
    const float* b1b = (const float*)d_in[5];
    const float* w2a = (const float*)d_in[6];
    const float* b2a = (const float*)d_in[7];
    const float* w2b = (const float*)d_in[8];
    const float* b2b = (const float*)d_in[9];
    const float* bn1g = (const float*)d_in[10];
    const float* bn1b = (const float*)d_in[11];
    const float* bn2g = (const float*)d_in[12];
    const float* bn2b = (const float*)d_in[13];
    const float* mw1 = (const float*)d_in[14];
    const float* mb1 = (const float*)d_in[15];
    const float* mw2 = (const float*)d_in[16];
    const float* mb2 = (const float*)d_in[17];
    float* out = (float*)d_out;

    char* w = (char*)d_ws;
    unsigned short* xb   = (unsigned short*)w;  w += (size_t)NN * FF * 2;
    unsigned short* agg1 = (unsigned short*)w;  w += (size_t)NN * FF * 2;
    unsigned short* h    = (unsigned short*)w;  w += (size_t)NN * HH * 2;  // h1 then h2
    unsigned short* agg2 = (unsigned short*)w;  w += (size_t)NN * HH * 2;
    float* stats = (float*)w;                   w += 1024 * 4;
    int* eidx = (int*)w;                        w += (size_t)EE * 4;
    unsigned int* packed = (unsigned int*)w;    w += (size_t)EE * 4;
    int* rowstart = (int*)w;                    w += (NN + 2) * 4;
    int* gbcount = (int*)w;                     w += (NBUCK + 2) * 4;
    int* gbstart = (int*)w;                     w += (NBUCK + 2) * 4;
    int* donecnt = (int*)w;                     w += 16;
    int* chunkhist = (int*)w;                   w += (size_t)NB_CH * NBUCK * 4;
    unsigned short* wt1a = (unsigned short*)w;  w += 8192 * 2;
    unsigned short* wt1b = (unsigned short*)w;  w += 16384 * 2;
    unsigned short* wt2a = (unsigned short*)w;  w += 16384 * 2;
    unsigned short* wt2b = (unsigned short*)w;  w += 16384 * 2;
    unsigned short* wtm1 = (unsigned short*)w;  w += 16384 * 2;
    unsigned short* wtm2 = (unsigned short*)w;  w += 2048 * 2;

    cvtprep_kernel<<<NB_CVT + TWB + NB_CH, 256, 0, stream>>>(
        x, xb, w1a, w1b, w2a, w2b, mw1, mw2,
        wt1a, wt1b, wt2a, wt2b, wtm1, wtm2, stats, donecnt, ei, chunkhist);

    chunkscan_kernel<<<NBUCK, 128, 0, stream>>>(chunkhist, gbcount, gbstart, rowstart, donecnt);
    p2_bin_kernel<<<NB_CH, 256, 0, stream>>>(ei, gbstart, chunkhist, packed);

    p3g1_kernel<<<NBUCK, 256, 0, stream>>>(packed, gbstart, xb, rowstart, eidx, agg1);

    mlp_kernel<FF><<<NBLK_LIN, 256, 0, stream>>>(agg1, wt1a, b1a, wt1b, b1b, h, stats, stats + 128);

    gather2_kernel<<<(NN + 7) / 8, 256, 0, stream>>>(
        h, rowstart, eidx, stats, stats + 128, bn1g, bn1b, agg2);
    mlp_kernel<HH><<<NBLK_LIN, 256, 0, stream>>>(agg2, wt2a, b2a, wt2b, b2b, h, stats + 256, stats + 384);

    final_kernel<<<NBLK_LIN, 256, 0, stream>>>(
        h, stats + 256, stats + 384, bn2g, bn2b,
        wtm1, mb1, wtm2, mb2, out, out + (size_t)NN * HH);
}

// Round 12
// 376.796 us; speedup vs baseline: 1.2746x; 1.1375x over previous
//
#include <hip/hip_runtime.h>
#include <cstdint>

// GIN model: N=100000, F=64, H=128, C=10, E=1600000.
// R12: exact R8 configuration (best measured: 378.6 us). R11's merged scan with
// per-block device-scope __threadfence regressed ~50us (782 L2-writeback fences);
// separate chunkscan + 1-block bscan is cheaper. 9 dispatches.

#define NN 100000
#define FF 64
#define HH 128
#define CC 10
#define EE 1600000
#define BN_EPS 1e-5f
#define MBLK 128
#define NBLK_LIN ((NN + MBLK - 1) / MBLK)  // 782
#define BSHIFT 7
#define NBUCK ((NN + 127) / 128)           // 782
#define CHUNK 16384
#define NB_CH ((EE + CHUNK - 1) / CHUNK)   // 98
#define NB_CVT 3125                        // 100000*64/8/256 exactly
#define TW (8192 + 4 * 16384 + 2048)
#define TWB ((TW + 255) / 256)
#define LDSE 3072

typedef __attribute__((ext_vector_type(8))) short bf16x8;
typedef __attribute__((ext_vector_type(4))) float f32x4;

__device__ inline unsigned short f2bf(float f) {
    unsigned int u = __float_as_uint(f);
    unsigned int r = (u + 0x7fffu + ((u >> 16) & 1u)) >> 16;
    return (unsigned short)r;
}
__device__ inline float b2f(unsigned short h) {
    return __uint_as_float(((unsigned int)h) << 16);
}
__device__ inline unsigned int pack2(float a, float b) {
    return (unsigned int)f2bf(a) | ((unsigned int)f2bf(b) << 16);
}
__device__ inline int detect_i64(const unsigned int* e) {
    return (e[1] | e[3] | e[5] | e[7]) == 0u;
}
__device__ inline int edge_dst(const void* eiv, int f, int e) {
    return f ? (int)((const long long*)eiv)[EE + e] : ((const int*)eiv)[EE + e];
}
__device__ inline int edge_src(const void* eiv, int f, int e) {
    return f ? (int)((const long long*)eiv)[e] : ((const int*)eiv)[e];
}

// ---------------- prep: x->bf16, weight transpose, stats zero, per-chunk dst hist ----------------
__global__ __launch_bounds__(256) void cvtprep_kernel(
    const float* __restrict__ x, unsigned short* __restrict__ xb,
    const float* __restrict__ w1a, const float* __restrict__ w1b,
    const float* __restrict__ w2a, const float* __restrict__ w2b,
    const float* __restrict__ mw1, const float* __restrict__ mw2,
    unsigned short* __restrict__ wt1a, unsigned short* __restrict__ wt1b,
    unsigned short* __restrict__ wt2a, unsigned short* __restrict__ wt2b,
    unsigned short* __restrict__ wtm1, unsigned short* __restrict__ wtm2,
    float* __restrict__ stats, const void* __restrict__ eiv,
    int* __restrict__ chunkhist) {
    __shared__ int hist[NBUCK];
    const int tid = threadIdx.x;
    const int b = blockIdx.x;
    if (b == 0)
        for (int i = tid; i < 512; i += 256) stats[i] = 0.f;
    if (b < NB_CVT) {
        int i = b * 256 + tid;
        float4 a = ((const float4*)x)[i * 2];
        float4 c = ((const float4*)x)[i * 2 + 1];
        uint4 o;
        o.x = pack2(a.x, a.y); o.y = pack2(a.z, a.w);
        o.z = pack2(c.x, c.y); o.w = pack2(c.z, c.w);
        ((uint4*)xb)[i] = o;
        return;
    }
    if (b < NB_CVT + TWB) {
        int idx = (b - NB_CVT) * 256 + tid;
        if (idx < 8192) {
            int k = idx >> 7, n = idx & 127;
            wt1a[n * 64 + k] = f2bf(w1a[idx]);
        } else if (idx < 8192 + 16384) {
            int t = idx - 8192; int k = t >> 7, n = t & 127;
            wt1b[n * 128 + k] = f2bf(w1b[t]);
        } else if (idx < 8192 + 2 * 16384) {
            int t = idx - (8192 + 16384); int k = t >> 7, n = t & 127;
            wt2a[n * 128 + k] = f2bf(w2a[t]);
        } else if (idx < 8192 + 3 * 16384) {
            int t = idx - (8192 + 2 * 16384); int k = t >> 7, n = t & 127;
            wt2b[n * 128 + k] = f2bf(w2b[t]);
        } else if (idx < 8192 + 4 * 16384) {
            int t = idx - (8192 + 3 * 16384); int k = t >> 7, n = t & 127;
            wtm1[n * 128 + k] = f2bf(mw1[t]);
        } else if (idx < TW) {
            int t = idx - (8192 + 4 * 16384); int n = t & 15, k = t >> 4;
            wtm2[n * 128 + k] = (n < CC) ? f2bf(mw2[k * CC + n]) : (unsigned short)0;
        }
        return;
    }
    // hist chunk
    const int ch = b - NB_CVT - TWB;
    const int f = detect_i64((const unsigned int*)eiv);
    for (int i = tid; i < NBUCK; i += 256) hist[i] = 0;
    __syncthreads();
    int beg = ch * CHUNK, end = min(beg + CHUNK, EE);
    for (int e = beg + tid; e < end; e += 256)
        atomicAdd(&hist[edge_dst(eiv, f, e) >> BSHIFT], 1);
    __syncthreads();
    for (int i = tid; i < NBUCK; i += 256) chunkhist[ch * NBUCK + i] = hist[i];
}

// ---------------- chunkscan: per-bucket prefix over chunks; totals -> gbcount ----------------
__global__ __launch_bounds__(128) void chunkscan_kernel(int* __restrict__ chunkhist,
                                                        int* __restrict__ gbcount) {
    __shared__ int s[128];
    const int b = blockIdx.x, tid = threadIdx.x;
    int v = (tid < NB_CH) ? chunkhist[tid * NBUCK + b] : 0;
    s[tid] = v;
    __syncthreads();
    for (int off = 1; off < 128; off <<= 1) {
        int t = (tid >= off) ? s[tid - off] : 0;
        __syncthreads();
        s[tid] += t;
        __syncthreads();
    }
    if (tid < NB_CH) chunkhist[tid * NBUCK + b] = s[tid] - v;  // relbase, in place
    if (tid == 127) gbcount[b] = s[127];
}

// ---------------- bucket scan ----------------
__global__ __launch_bounds__(1024) void bscan_kernel(const int* __restrict__ gbcount,
                                                     int* __restrict__ gbstart,
                                                     int* __restrict__ rowstart) {
    __shared__ int s[1024];
    const int tid = threadIdx.x;
    int v = (tid < NBUCK) ? gbcount[tid] : 0;
    s[tid] = v;
    __syncthreads();
    for (int off = 1; off < 1024; off <<= 1) {
        int t = (tid >= off) ? s[tid - off] : 0;
        __syncthreads();
        s[tid] += t;
        __syncthreads();
    }
    if (tid < NBUCK) gbstart[tid] = s[tid] - v;
    if (tid == 0) { gbstart[NBUCK] = EE; rowstart[NN] = EE; }
}

// ---------------- p2: single-pass bin (packed src | dstlow<<17) ----------------
__global__ __launch_bounds__(256) void p2_bin_kernel(const void* __restrict__ eiv,
                                                     const int* __restrict__ gbstart,
                                                     const int* __restrict__ relbase,
                                                     unsigned int* __restrict__ packed) {
    __shared__ int hist[NBUCK];
    __shared__ int basep[NBUCK];
    const int tid = threadIdx.x;
    const int ch = blockIdx.x;
    const int f = detect_i64((const unsigned int*)eiv);
    for (int i = tid; i < NBUCK; i += 256) {
        hist[i] = 0;
        basep[i] = gbstart[i] + relbase[ch * NBUCK + i];
    }
    __syncthreads();
    int beg = ch * CHUNK, end = min(beg + CHUNK, EE);
    for (int e = beg + tid; e < end; e += 256) {
        int s = edge_src(eiv, f, e);
        int d = edge_dst(eiv, f, e);
        int b = d >> BSHIFT;
        int r = atomicAdd(&hist[b], 1);
        packed[basep[b] + r] = (unsigned int)s | ((unsigned int)(d & 127) << 17);
    }
}

// ---------------- p3+gather1 fused: sort bucket (LDS) -> rowstart/eidx; gather agg1 ----------------
__global__ __launch_bounds__(256) void p3g1_kernel(const unsigned int* __restrict__ packed,
                                                   const int* __restrict__ gbstart,
                                                   const unsigned short* __restrict__ xb,
                                                   int* __restrict__ rowstart,
                                                   int* __restrict__ eidx,
                                                   unsigned short* __restrict__ agg1) {
    __shared__ int hist[128];
    __shared__ int excl[128];
    __shared__ int sc[128];
    __shared__ int lidx[LDSE];
    const int tid = threadIdx.x;
    const int b = blockIdx.x;
    const int bstart = gbstart[b], bend = gbstart[b + 1];
    const int cnt = bend - bstart;
    if (tid < 128) hist[tid] = 0;
    __syncthreads();
    for (int e = bstart + tid; e < bend; e += 256)
        atomicAdd(&hist[packed[e] >> 17], 1);
    __syncthreads();
    int v = (tid < 128) ? hist[tid] : 0;
    if (tid < 128) sc[tid] = v;
    __syncthreads();
    for (int off = 1; off < 128; off <<= 1) {
        int t = (tid < 128 && tid >= off) ? sc[tid - off] : 0;
        __syncthreads();
        if (tid < 128) sc[tid] += t;
        __syncthreads();
    }
    if (tid < 128) {
        excl[tid] = sc[tid] - v;
        hist[tid] = 0;
        int node = b * 128 + tid;
        if (node < NN) rowstart[node] = bstart + sc[tid] - v;
    }
    __syncthreads();
    const bool inl = (cnt <= LDSE);
    for (int e = bstart + tid; e < bend; e += 256) {
        unsigned int p = packed[e];
        int dl = p >> 17;
        int r = atomicAdd(&hist[dl], 1);
        int pos = excl[dl] + r;
        int sv = (int)(p & 0x1FFFFu);
        eidx[bstart + pos] = sv;
        if (inl) lidx[pos] = sv;
    }
    __syncthreads();
    const int* ep = inl ? (const int*)lidx : (eidx + bstart);
    const int g = tid >> 3, l8 = tid & 7, c = l8 * 8;
    for (int r4 = 0; r4 < 4; r4++) {
        int nl = r4 * 32 + g;
        int node = b * 128 + nl;
        if (node >= NN) continue;
        float acc[8];
        uint4 sv4 = *(const uint4*)(xb + (size_t)node * FF + c);
        {
            const unsigned int* wv = (const unsigned int*)&sv4;
#pragma unroll
            for (int p = 0; p < 4; p++) {
                acc[p * 2] = b2f((unsigned short)(wv[p] & 0xffff));
                acc[p * 2 + 1] = b2f((unsigned short)(wv[p] >> 16));
            }
        }
        auto addv = [&](uint4 u) {
            const unsigned int* wv = (const unsigned int*)&u;
#pragma unroll
            for (int p = 0; p < 4; p++) {
                acc[p * 2] += b2f((unsigned short)(wv[p] & 0xffff));
                acc[p * 2 + 1] += b2f((unsigned short)(wv[p] >> 16));
            }
        };
        int beg2 = excl[nl], cend = beg2 + hist[nl];
        int j = beg2;
        for (; j + 3 < cend; j += 4) {
            int i0 = ep[j], i1 = ep[j + 1], i2 = ep[j + 2], i3 = ep[j + 3];
            uint4 v0 = *(const uint4*)(xb + (size_t)i0 * FF + c);
            uint4 v1 = *(const uint4*)(xb + (size_t)i1 * FF + c);
            uint4 v2 = *(const uint4*)(xb + (size_t)i2 * FF + c);
            uint4 v3 = *(const uint4*)(xb + (size_t)i3 * FF + c);
            addv(v0); addv(v1); addv(v2); addv(v3);
        }
        for (; j < cend; j++)
            addv(*(const uint4*)(xb + (size_t)ep[j] * FF + c));
        uint4 o;
        o.x = pack2(acc[0], acc[1]); o.y = pack2(acc[2], acc[3]);
        o.z = pack2(acc[4], acc[5]); o.w = pack2(acc[6], acc[7]);
        *(uint4*)(agg1 + (size_t)node * FF + c) = o;
    }
}

// ---------------- gather2: uint2 loads, fused BN1 ----------------
__global__ __launch_bounds__(256) void gather2_kernel(const unsigned short* __restrict__ h,
                                                      const int* __restrict__ rowstart,
                                                      const int* __restrict__ eidx,
                                                      const float* __restrict__ statsum,
                                                      const float* __restrict__ statsq,
                                                      const float* __restrict__ bng,
                                                      const float* __restrict__ bnb,
                                                      unsigned short* __restrict__ agg2) {
    int node = blockIdx.x * 8 + (threadIdx.x >> 5);
    const int l32 = threadIdx.x & 31;
    const int c = l32 * 4;
    if (node >= NN) return;
    float scl[4], off[4];
#pragma unroll
    for (int k = 0; k < 4; k++) {
        float m = statsum[c + k] * (1.0f / NN);
        float vv = statsq[c + k] * (1.0f / NN) - m * m;
        scl[k] = bng[c + k] * rsqrtf(vv + BN_EPS);
        off[k] = bnb[c + k] - m * scl[k];
    }
    float acc[4] = {0.f, 0.f, 0.f, 0.f};
    auto addv = [&](uint2 u) {
        acc[0] += fmaxf(fmaf(b2f((unsigned short)(u.x & 0xffff)), scl[0], off[0]), 0.f);
        acc[1] += fmaxf(fmaf(b2f((unsigned short)(u.x >> 16)), scl[1], off[1]), 0.f);
        acc[2] += fmaxf(fmaf(b2f((unsigned short)(u.y & 0xffff)), scl[2], off[2]), 0.f);
        acc[3] += fmaxf(fmaf(b2f((unsigned short)(u.y >> 16)), scl[3], off[3]), 0.f);
    };
    addv(*(const uint2*)(h + (size_t)node * HH + c));
    int beg = rowstart[node], end = rowstart[node + 1];
    int j = beg;
    for (; j + 3 < end; j += 4) {
        int i0 = eidx[j], i1 = eidx[j + 1], i2 = eidx[j + 2], i3 = eidx[j + 3];
        uint2 v0 = *(const uint2*)(h + (size_t)i0 * HH + c);
        uint2 v1 = *(const uint2*)(h + (size_t)i1 * HH + c);
        uint2 v2 = *(const uint2*)(h + (size_t)i2 * HH + c);
        uint2 v3 = *(const uint2*)(h + (size_t)i3 * HH + c);
        addv(v0); addv(v1); addv(v2); addv(v3);
    }
    for (; j < end; j++)
        addv(*(const uint2*)(h + (size_t)eidx[j] * HH + c));
    uint2 o;
    o.x = pack2(acc[0], acc[1]);
    o.y = pack2(acc[2], acc[3]);
    *(uint2*)(agg2 + (size_t)node * HH + c) = o;
}

// ---------------- fused MLP (LDS-staged A and W) ----------------
template <int KIN>
__global__ __launch_bounds__(256) void mlp_kernel(const unsigned short* __restrict__ in,
                                                  const unsigned short* __restrict__ wTa,
                                                  const float* __restrict__ ba,
                                                  const unsigned short* __restrict__ wTb,
                                                  const float* __restrict__ bb,
                                                  unsigned short* __restrict__ out,
                                                  float* __restrict__ bnsum,
                                                  float* __restrict__ bnsq) {
    constexpr int KLDA = KIN + 8;
    constexpr int CH = KIN / 8;
    __shared__ __attribute__((aligned(16))) unsigned short sA[MBLK * 136];
    __shared__ __attribute__((aligned(16))) unsigned short sW[128 * 136];
    __shared__ float sSt[256];
    __shared__ float sB[256];

    const int tid = threadIdx.x;
    const int wave = tid >> 6, lane = tid & 63;
    const int quad = lane >> 4, l16 = lane & 15;
    const long long row0 = (long long)blockIdx.x * MBLK;

    sSt[tid] = 0.f;
    if (tid < 128) sB[tid] = ba[tid];
    else sB[tid] = bb[tid - 128];

    for (int i = tid; i < 128 * CH; i += 256)
        *(uint4*)(sW + (i / CH) * KLDA + (i % CH) * 8) = ((const uint4*)wTa)[i];
    for (int i = tid; i < MBLK * CH; i += 256) {
        int r = i / CH, c = i % CH;
        uint4 v = {0u, 0u, 0u, 0u};
        if (row0 + r < NN) v = *(const uint4*)(in + (row0 + r) * KIN + c * 8);
        *(uint4*)(sA + r * KLDA + c * 8) = v;
    }
    __syncthreads();

    f32x4 acc1[2][8];
#pragma unroll
    for (int t = 0; t < 2; t++)
#pragma unroll
        for (int n = 0; n < 8; n++) acc1[t][n] = 0.f;
#pragma unroll
    for (int ks = 0; ks < KIN / 32; ks++) {
        bf16x8 a0 = *(const bf16x8*)(sA + (wave * 32 + l16) * KLDA + ks * 32 + quad * 8);
        bf16x8 a1 = *(const bf16x8*)(sA + (wave * 32 + 16 + l16) * KLDA + ks * 32 + quad * 8);
#pragma unroll
        for (int nt = 0; nt < 8; nt++) {
            bf16x8 b = *(const bf16x8*)(sW + (nt * 16 + l16) * KLDA + ks * 32 + quad * 8);
            acc1[0][nt] = __builtin_amdgcn_mfma_f32_16x16x32_bf16(a0, b, acc1[0][nt], 0, 0, 0);
            acc1[1][nt] = __builtin_amdgcn_mfma_f32_16x16x32_bf16(a1, b, acc1[1][nt], 0, 0, 0);
        }
    }
    __syncthreads();

#pragma unroll
    for (int nt = 0; nt < 8; nt++) {
        const int col = nt * 16 + l16;
        const float bcol = sB[col];
#pragma unroll
        for (int t = 0; t < 2; t++)
#pragma unroll
            for (int r = 0; r < 4; r++) {
                int rl = wave * 32 + t * 16 + quad * 4 + r;
                sA[rl * 136 + col] = f2bf(fmaxf(acc1[t][nt][r] + bcol, 0.f));
            }
    }
    for (int i = tid; i < 128 * 16; i += 256)
        *(uint4*)(sW + (i >> 4) * 136 + (i & 15) * 8) = ((const uint4*)wTb)[i];
    __syncthreads();

    f32x4 acc2[2][8];
#pragma unroll
    for (int t = 0; t < 2; t++)
#pragma unroll
        for (int n = 0; n < 8; n++) acc2[t][n] = 0.f;
#pragma unroll
    for (int ks = 0; ks < 4; ks++) {
        bf16x8 a0 = *(const bf16x8*)(sA + (wave * 32 + l16) * 136 + ks * 32 + quad * 8);
        bf16x8 a1 = *(const bf16x8*)(sA + (wave * 32 + 16 + l16) * 136 + ks * 32 + quad * 8);
#pragma unroll
        for (int nt = 0; nt < 8; nt++) {
            bf16x8 b = *(const bf16x8*)(sW + (nt * 16 + l16) * 136 + ks * 32 + quad * 8);
            acc2[0][nt] = __builtin_amdgcn_mfma_f32_16x16x32_bf16(a0, b, acc2[0][nt], 0, 0, 0);
            acc2[1][nt] = __builtin_amdgcn_mfma_f32_16x16x32_bf16(a1, b, acc2[1][nt], 0, 0, 0);
        }
    }
    __syncthreads();

#pragma unroll
    for (int nt = 0; nt < 8; nt++) {
        const int col = nt * 16 + l16;
        const float bcol = sB[128 + col];
        float ls = 0.f, lq = 0.f;
#pragma unroll
        for (int t = 0; t < 2; t++)
#pragma unroll
            for (int r = 0; r < 4; r++) {
                int rl = wave * 32 + t * 16 + quad * 4 + r;
                float v = acc2[t][nt][r] + bcol;
                if (row0 + rl < NN) { ls += v; lq += v * v; }
                sA[rl * 136 + col] = f2bf(v);
            }
        ls += __shfl_down(ls, 32); ls += __shfl_down(ls, 16);
        lq += __shfl_down(lq, 32); lq += __shfl_down(lq, 16);
        if (lane < 16) { atomicAdd(&sSt[col], ls); atomicAdd(&sSt[128 + col], lq); }
    }
    __syncthreads();

    for (int i = tid; i < MBLK * 16; i += 256) {
        int r = i >> 4, c = i & 15;
        if (row0 + r < NN)
            *(uint4*)(out + (row0 + r) * 128 + c * 8) = *(const uint4*)(sA + r * 136 + c * 8);
    }
    if (tid < 128) atomicAdd(&bnsum[tid], sSt[tid]);
    else atomicAdd(&bnsq[tid - 128], sSt[tid]);
}

// ---------------- final ----------------
__global__ __launch_bounds__(256) void final_kernel(const unsigned short* __restrict__ h2,
                                                    const float* __restrict__ statsum,
                                                    const float* __restrict__ statsq,
                                                    const float* __restrict__ bng,
                                                    const float* __restrict__ bnb,
                                                    const unsigned short* __restrict__ wTm1,
                                                    const float* __restrict__ mb1,
                                                    const unsigned short* __restrict__ wTm2,
                                                    const float* __restrict__ mb2,
                                                    float* __restrict__ latent,
                                                    float* __restrict__ cls) {
    __shared__ __attribute__((aligned(16))) unsigned short sA[MBLK * 136];
    __shared__ __attribute__((aligned(16))) unsigned short sW[128 * 136];
    __shared__ float sBN[256];
    __shared__ float sB1[128];

    const int tid = threadIdx.x;
    const int wave = tid >> 6, lane = tid & 63;
    const int quad = lane >> 4, l16 = lane & 15;
    const long long row0 = (long long)blockIdx.x * MBLK;

    if (tid < 128) {
        float mean = statsum[tid] * (1.0f / NN);
        float var = statsq[tid] * (1.0f / NN) - mean * mean;
        float sc = bng[tid] * rsqrtf(var + BN_EPS);
        sBN[tid] = sc;
        sBN[128 + tid] = bnb[tid] - mean * sc;
        sB1[tid] = mb1[tid];
    }
    for (int i = tid; i < 128 * 16; i += 256)
        *(uint4*)(sW + (i >> 4) * 136 + (i & 15) * 8) = ((const uint4*)wTm1)[i];
    __syncthreads();

    for (int i = tid; i < MBLK * 16; i += 256) {
        int r = i >> 4, c = i & 15;
        bool live = (row0 + r < NN);
        uint4 hv = {0u, 0u, 0u, 0u};
        if (live) hv = *(const uint4*)(h2 + (row0 + r) * 128 + c * 8);
        const unsigned int* wv = (const unsigned int*)&hv;
        float vs[8];
#pragma unroll
        for (int p = 0; p < 4; p++) {
            int cc = c * 8 + p * 2;
            vs[p * 2]     = fmaxf(fmaf(b2f((unsigned short)(wv[p] & 0xffff)), sBN[cc], sBN[128 + cc]), 0.f);
            vs[p * 2 + 1] = fmaxf(fmaf(b2f((unsigned short)(wv[p] >> 16)), sBN[cc + 1], sBN[129 + cc]), 0.f);
        }
        if (live) {
            float4 f0 = {vs[0], vs[1], vs[2], vs[3]};
            float4 f1 = {vs[4], vs[5], vs[6], vs[7]};
            float* lp = latent + (row0 + r) * 128 + c * 8;
            *(float4*)lp = f0;
            *(float4*)(lp + 4) = f1;
        }
        uint4 o;
        o.x = pack2(vs[0], vs[1]); o.y = pack2(vs[2], vs[3]);
        o.z = pack2(vs[4], vs[5]); o.w = pack2(vs[6], vs[7]);
        *(uint4*)(sA + r * 136 + c * 8) = o;
    }
    __syncthreads();

    f32x4 acc1[2][8];
#pragma unroll
    for (int t = 0; t < 2; t++)
#pragma unroll
        for (int n = 0; n < 8; n++) acc1[t][n] = 0.f;
#pragma unroll
    for (int ks = 0; ks < 4; ks++) {
        bf16x8 av0 = *(const bf16x8*)(sA + (wave * 32 + l16) * 136 + ks * 32 + quad * 8);
        bf16x8 av1 = *(const bf16x8*)(sA + (wave * 32 + 16 + l16) * 136 + ks * 32 + quad * 8);
#pragma unroll
        for (int nt = 0; nt < 8; nt++) {
            bf16x8 b = *(const bf16x8*)(sW + (nt * 16 + l16) * 136 + ks * 32 + quad * 8);
            acc1[0][nt] = __builtin_amdgcn_mfma_f32_16x16x32_bf16(av0, b, acc1[0][nt], 0, 0, 0);
            acc1[1][nt] = __builtin_amdgcn_mfma_f32_16x16x32_bf16(av1, b, acc1[1][nt], 0, 0, 0);
        }
    }
    __syncthreads();

#pragma unroll
    for (int nt = 0; nt < 8; nt++) {
        const int col = nt * 16 + l16;
        const float bcol = sB1[col];
#pragma unroll
        for (int t = 0; t < 2; t++)
#pragma unroll
            for (int r = 0; r < 4; r++) {
                int rl = wave * 32 + t * 16 + quad * 4 + r;
                sA[rl * 136 + col] = f2bf(fmaxf(acc1[t][nt][r] + bcol, 0.f));
            }
    }
    if (tid < 256)
        *(uint4*)(sW + (tid >> 4) * 136 + (tid & 15) * 8) = ((const uint4*)wTm2)[tid];
    __syncthreads();

    f32x4 acc2[2];
    acc2[0] = 0.f; acc2[1] = 0.f;
#pragma unroll
    for (int ks = 0; ks < 4; ks++) {
        bf16x8 av0 = *(const bf16x8*)(sA + (wave * 32 + l16) * 136 + ks * 32 + quad * 8);
        bf16x8 av1 = *(const bf16x8*)(sA + (wave * 32 + 16 + l16) * 136 + ks * 32 + quad * 8);
        bf16x8 b = *(const bf16x8*)(sW + l16 * 136 + ks * 32 + quad * 8);
        acc2[0] = __builtin_amdgcn_mfma_f32_16x16x32_bf16(av0, b, acc2[0], 0, 0, 0);
        acc2[1] = __builtin_amdgcn_mfma_f32_16x16x32_bf16(av1, b, acc2[1], 0, 0, 0);
    }
    __syncthreads();

    float* sOf = (float*)sA;
    if (l16 < CC) {
        const float bc = mb2[l16];
#pragma unroll
        for (int t = 0; t < 2; t++)
#pragma unroll
            for (int r = 0; r < 4; r++) {
                int rl = wave * 32 + t * 16 + quad * 4 + r;
                sOf[rl * CC + l16] = acc2[t][r] + bc;
            }
    }
    __syncthreads();
    for (int i = tid; i < MBLK * CC; i += 256) {
        long long gi = row0 * CC + i;
        if (gi < (long long)NN * CC) cls[gi] = sOf[i];
    }
}

extern "C" void kernel_launch(void* const* d_in, const int* in_sizes, int n_in,
                              void* d_out, int out_size, void* d_ws, size_t ws_size,
                              hipStream_t stream) {
    const float* x   = (const float*)d_in[0];
    const void* ei   = d_in[1];
    const float* w1a = (const float*)d_in[2];
    const float* b1a = (const float*)d_in[3];
    const float* w1b = (const float*)d_in[4];
    const float* b1b = (const float*)d_in[5];
    const float* w2a = (const float*)d_in[6];
    const float* b2a = (const float*)d_in[7];
    const float* w2b = (const float*)d_in[8];
    const float* b2b = (const float*)d_in[9];
    const float* bn1g = (const float*)d_in[10];
    const float* bn1b = (const float*)d_in[11];
    const float* bn2g = (const float*)d_in[12];
    const float* bn2b = (const float*)d_in[13];
    const float* mw1 = (const float*)d_in[14];
    const float* mb1 = (const float*)d_in[15];
    const float* mw2 = (const float*)d_in[16];
    const float* mb2 = (const float*)d_in[17];
    float* out = (float*)d_out;

    char* w = (char*)d_ws;
    unsigned short* xb   = (unsigned short*)w;  w += (size_t)NN * FF * 2;
    unsigned short* agg1 = (unsigned short*)w;  w += (size_t)NN * FF * 2;
    unsigned short* h    = (unsigned short*)w;  w += (size_t)NN * HH * 2;  // h1 then h2
    unsigned short* agg2 = (unsigned short*)w;  w += (size_t)NN * HH * 2;
    float* stats = (float*)w;                   w += 1024 * 4;
    int* eidx = (int*)w;                        w += (size_t)EE * 4;
    unsigned int* packed = (unsigned int*)w;    w += (size_t)EE * 4;
    int* rowstart = (int*)w;                    w += (NN + 2) * 4;
    int* gbcount = (int*)w;                     w += (NBUCK + 2) * 4;
    int* gbstart = (int*)w;                     w += (NBUCK + 2) * 4;
    int* chunkhist = (int*)w;                   w += (size_t)NB_CH * NBUCK * 4;
    unsigned short* wt1a = (unsigned short*)w;  w += 8192 * 2;
    unsigned short* wt1b = (unsigned short*)w;  w += 16384 * 2;
    unsigned short* wt2a = (unsigned short*)w;  w += 16384 * 2;
    unsigned short* wt2b = (unsigned short*)w;  w += 16384 * 2;
    unsigned short* wtm1 = (unsigned short*)w;  w += 16384 * 2;
    unsigned short* wtm2 = (unsigned short*)w;  w += 2048 * 2;

    cvtprep_kernel<<<NB_CVT + TWB + NB_CH, 256, 0, stream>>>(
        x, xb, w1a, w1b, w2a, w2b, mw1, mw2,
        wt1a, wt1b, wt2a, wt2b, wtm1, wtm2, stats, ei, chunkhist);

    chunkscan_kernel<<<NBUCK, 128, 0, stream>>>(chunkhist, gbcount);
    bscan_kernel<<<1, 1024, 0, stream>>>(gbcount, gbstart, rowstart);
    p2_bin_kernel<<<NB_CH, 256, 0, stream>>>(ei, gbstart, chunkhist, packed);

    p3g1_kernel<<<NBUCK, 256, 0, stream>>>(packed, gbstart, xb, rowstart, eidx, agg1);

    mlp_kernel<FF><<<NBLK_LIN, 256, 0, stream>>>(agg1, wt1a, b1a, wt1b, b1b, h, stats, stats + 128);

    gather2_kernel<<<(NN + 7) / 8, 256, 0, stream>>>(
        h, rowstart, eidx, stats, stats + 128, bn1g, bn1b, agg2);
    mlp_kernel<HH><<<NBLK_LIN, 256, 0, stream>>>(agg2, wt2a, b2a, wt2b, b2b, h, stats + 256, stats + 384);

    final_kernel<<<NBLK_LIN, 256, 0, stream>>>(
        h, stats + 256, stats + 384, bn2g, bn2b,
        wtm1, mb1, wtm2, mb2, out, out + (size_t)NN * HH);
}